// Round 9
// baseline (60162.329 us; speedup 1.0000x reference)
//
#include <hip/hip_runtime.h>
#include <hip/hip_cooperative_groups.h>
#include <math.h>

namespace cg = cooperative_groups;

#define Bz  64
#define Ez  512
#define Hz  1024
#define SLz 128
#define TLz 128
#define NBLK 256
#define TPB 512
#define NGRP 16

// packed x layout: element (k, b) at ((k>>2)<<8) + (b<<2) + (k&3)
#define XPK(k, b) ((((k) >> 2) << 8) + ((b) << 2) + ((k) & 3))

// smem_f float layout (lstm phase):
//   xt [2][16][64][4]   = 8192 floats  (staged x tiles: half, kq, batch, 4k)
//   zb [2][16][64]      = 2048 floats  (partial z)
// total 10240 floats = 40 KiB (+2 KiB smem_i).  Weights are NOT staged to
// LDS any more: they are wave-uniform and are read via the scalar path
// (readfirstlane-forced uniform addresses -> s_load), freeing the LDS pipe
// from 8192 broadcast ds_read_b128 per phase (~41 us/phase).
#define ZB_OFF 8192

// ---------------------------------------------------------------------------
// Two-level grid barrier (proven in round 6). bar layout (ints, 64B lines):
//   [g*16] arrival counter group g (g = blockIdx.x % NGRP)
//   [NGRP*16] root counter ; [NGRP*16+16] release flag (epoch)
// Counters monotone; epoch e target = e*members. No resets -> no races.
// ---------------------------------------------------------------------------
__device__ __forceinline__ void gsync(int* bar, int e) {
    __syncthreads();
    if (threadIdx.x == 0) {
        __threadfence();   // release
        int* gcnt = bar + ((blockIdx.x & (NGRP - 1)) << 4);
        int* rcnt = bar + (NGRP << 4);
        int* flag = bar + (NGRP << 4) + 16;
        const int gsz = NBLK / NGRP;
        bool done = false;
        if (__hip_atomic_fetch_add(gcnt, 1, __ATOMIC_ACQ_REL,
                                   __HIP_MEMORY_SCOPE_AGENT) == e * gsz - 1) {
            if (__hip_atomic_fetch_add(rcnt, 1, __ATOMIC_ACQ_REL,
                                       __HIP_MEMORY_SCOPE_AGENT) == e * NGRP - 1) {
                __hip_atomic_store(flag, e, __ATOMIC_RELEASE,
                                   __HIP_MEMORY_SCOPE_AGENT);
                done = true;
            }
        }
        if (!done) {
            while (__hip_atomic_load(flag, __ATOMIC_ACQUIRE,
                                     __HIP_MEMORY_SCOPE_AGENT) < e) {
                __builtin_amdgcn_s_sleep(2);
            }
        }
        __threadfence();   // acquire
    }
    __syncthreads();
}

// ---------------------------------------------------------------------------
// One LSTM layer, one timestep, one unit-group (4 hidden units) per block.
// 8 waves: wave w -> half = w>>2 (K split in 2), ur = w&3 (unit in group).
// Per round (64 k per half): stage x tiles [2][16][64][4] to LDS (4
// float4/thread, once per block), barrier, compute, barrier.
// Weight reads: 4 float4/iter at wave-uniform addresses (readfirstlane-
// derived wave id) -> scalar loads, SGPR operands to v_fma.
// Accumulation order is bit-identical to the round-8 passing kernel.
// ---------------------------------------------------------------------------
template <bool EMB>
__device__ __forceinline__ void lstm_phase(
    float* __restrict__ smem_f,
    const float* __restrict__ embed, const int* __restrict__ ids,
    int ids_stride, int ids_off,
    const float* __restrict__ xPK, int Dx,
    const float* __restrict__ Wih, const float* __restrict__ Whh,
    const float* __restrict__ bias,
    const float* __restrict__ hinPK, float* __restrict__ houtPK,
    float* __restrict__ cst)
{
    float* xt = smem_f;
    float* zb = smem_f + ZB_OFF;
    const int tid  = threadIdx.x;
    const int lane = tid & 63;
    const int uw   = __builtin_amdgcn_readfirstlane(tid >> 6); // wave id, SGPR
    const int half = uw >> 2;         // K-split half (wave-uniform)
    const int ur   = uw & 3;          // unit within group (wave-uniform)
    const int hu0  = blockIdx.x << 2; // unit-group base
    const int Kh   = (Dx + Hz) >> 1;

    // x staging role: batch sb, combo group cg; combos c = cg + 8j (j=0..3)
    // combo c: half = c>>4, kq = c&15 (16 kq x 4 k = 64 k per half per round)
    const int sb = tid & 63;
    const int cg = tid >> 6;          // 0..7 (wave-uniform by construction)
    const float* xrs = nullptr;
    if (EMB) {
        const int idx = ids[sb * ids_stride + ids_off];
        xrs = embed + (size_t)idx * Dx;
    }

    float acc0 = 0.f, acc1 = 0.f, acc2 = 0.f, acc3 = 0.f;

    // wave-uniform weight row index for this wave's unit (gate g row = g*1024 + r0)
    const int r0 = hu0 + ur;

    for (int kt = 0; kt < Kh; kt += 64) {
        // ---- stage both halves' x tiles (4 float4/thread, once/block) ----
        #pragma unroll
        for (int j = 0; j < 4; ++j) {
            const int c  = cg + (j << 3);      // 0..31
            const int h  = c >> 4, kq = c & 15;
            const int kg = h * Kh + kt + (kq << 2);
            const float* src;
            if (kg < Dx) {
                if (EMB) src = xrs + kg;
                else     src = xPK + (kg << 6) + (sb << 2);
            } else {
                src = hinPK + ((kg - Dx) << 6) + (sb << 2);
            }
            *(float4*)&xt[(h << 12) + (kq << 8) + (sb << 2)] = *(const float4*)src;
        }
        __syncthreads();

        // wave-uniform weight base pointers for this round (rounds are
        // 64-aligned and Dx is a multiple of 64 -> no straddle)
        const int kgb = half * Kh + kt;
        const float* wp0; const float* wp1; const float* wp2; const float* wp3;
        if (kgb < Dx) {
            wp0 = Wih + (size_t)r0 * Dx + kgb;
            wp1 = Wih + (size_t)(1024 + r0) * Dx + kgb;
            wp2 = Wih + (size_t)(2048 + r0) * Dx + kgb;
            wp3 = Wih + (size_t)(3072 + r0) * Dx + kgb;
        } else {
            const int kh = kgb - Dx;
            wp0 = Whh + ((size_t)r0 << 10) + kh;
            wp1 = Whh + ((size_t)(1024 + r0) << 10) + kh;
            wp2 = Whh + ((size_t)(2048 + r0) << 10) + kh;
            wp3 = Whh + ((size_t)(3072 + r0) << 10) + kh;
        }

        // ---- compute round: x from LDS, w via scalar loads ----
        #pragma unroll 4
        for (int kl = 0; kl < 64; kl += 4) {
            const float4 xv = *(const float4*)
                &xt[(half << 12) + ((kl >> 2) << 8) + (lane << 2)];
            const float4 w0 = *(const float4*)(wp0 + kl);
            const float4 w1 = *(const float4*)(wp1 + kl);
            const float4 w2 = *(const float4*)(wp2 + kl);
            const float4 w3 = *(const float4*)(wp3 + kl);
            acc0 = fmaf(w0.x, xv.x, acc0); acc0 = fmaf(w0.y, xv.y, acc0);
            acc0 = fmaf(w0.z, xv.z, acc0); acc0 = fmaf(w0.w, xv.w, acc0);
            acc1 = fmaf(w1.x, xv.x, acc1); acc1 = fmaf(w1.y, xv.y, acc1);
            acc1 = fmaf(w1.z, xv.z, acc1); acc1 = fmaf(w1.w, xv.w, acc1);
            acc2 = fmaf(w2.x, xv.x, acc2); acc2 = fmaf(w2.y, xv.y, acc2);
            acc2 = fmaf(w2.z, xv.z, acc2); acc2 = fmaf(w2.w, xv.w, acc2);
            acc3 = fmaf(w3.x, xv.x, acc3); acc3 = fmaf(w3.y, xv.y, acc3);
            acc3 = fmaf(w3.z, xv.z, acc3); acc3 = fmaf(w3.w, xv.w, acc3);
        }
        __syncthreads();
    }

    // partial z to LDS: zb[half][g*4+ur][lane]  (round 8 verbatim)
    zb[(half << 10) + (0 << 8) + (ur << 6) + lane] = acc0;
    zb[(half << 10) + (1 << 8) + (ur << 6) + lane] = acc1;
    zb[(half << 10) + (2 << 8) + (ur << 6) + lane] = acc2;
    zb[(half << 10) + (3 << 8) + (ur << 6) + lane] = acc3;
    __syncthreads();

    if (tid < 256) {
        const int u = tid >> 6, b = tid & 63;
        const int base = (u << 6) + b;
        const float zi = zb[base]         + zb[1024 + base]         + bias[(hu0 + u)];
        const float zf = zb[256 + base]   + zb[1024 + 256 + base]   + bias[1024 + (hu0 + u)];
        const float zg = zb[512 + base]   + zb[1024 + 512 + base]   + bias[2048 + (hu0 + u)];
        const float zo = zb[768 + base]   + zb[1024 + 768 + base]   + bias[3072 + (hu0 + u)];
        const int hk = hu0 + u;
        const float cold = cst[(hk << 6) + b];
        const float ig = 1.0f / (1.0f + expf(-zi));
        const float fg = 1.0f / (1.0f + expf(-zf));
        const float gg = tanhf(zg);
        const float og = 1.0f / (1.0f + expf(-zo));
        const float cnew = fg * cold + ig * gg;
        cst[(hk << 6) + b] = cnew;
        houtPK[XPK(hk, b)] = og * tanhf(cnew);
    }
}

// logits[row][b] = linb[row] + sum_k linW[row][k] * h1[k][b]
// block = 4 rows; 8 waves K-split 8; weights read via scalar path
// (wave-uniform addresses), no LDS staging.
__device__ __forceinline__ void head_phase(
    float* __restrict__ smem_f,
    const float* __restrict__ linW, const float* __restrict__ linb,
    const float* __restrict__ h1PK, float* __restrict__ logits)
{
    float* zb = smem_f;          // [8][4][64] = 2048
    const int tid = threadIdx.x, lane = tid & 63;
    const int uwv = __builtin_amdgcn_readfirstlane(tid >> 6);  // wave id
    const int hu0 = blockIdx.x << 2;
    float a0 = 0.f, a1 = 0.f, a2 = 0.f, a3 = 0.f;
    const int kb = uwv << 7;   // 128-k slice per wave (wave-uniform)
    const float* w0p = linW + (((size_t)(hu0 + 0)) << 10) + kb;
    const float* w1p = linW + (((size_t)(hu0 + 1)) << 10) + kb;
    const float* w2p = linW + (((size_t)(hu0 + 2)) << 10) + kb;
    const float* w3p = linW + (((size_t)(hu0 + 3)) << 10) + kb;
    #pragma unroll 4
    for (int kl = 0; kl < 128; kl += 4) {
        const int k = kb + kl;
        const float4 xv = *(const float4*)(h1PK + ((k >> 2) << 8) + (lane << 2));
        const float4 w0 = *(const float4*)(w0p + kl);
        const float4 w1 = *(const float4*)(w1p + kl);
        const float4 w2 = *(const float4*)(w2p + kl);
        const float4 w3 = *(const float4*)(w3p + kl);
        a0 = fmaf(w0.x, xv.x, a0); a0 = fmaf(w0.y, xv.y, a0);
        a0 = fmaf(w0.z, xv.z, a0); a0 = fmaf(w0.w, xv.w, a0);
        a1 = fmaf(w1.x, xv.x, a1); a1 = fmaf(w1.y, xv.y, a1);
        a1 = fmaf(w1.z, xv.z, a1); a1 = fmaf(w1.w, xv.w, a1);
        a2 = fmaf(w2.x, xv.x, a2); a2 = fmaf(w2.y, xv.y, a2);
        a2 = fmaf(w2.z, xv.z, a2); a2 = fmaf(w2.w, xv.w, a2);
        a3 = fmaf(w3.x, xv.x, a3); a3 = fmaf(w3.y, xv.y, a3);
        a3 = fmaf(w3.z, xv.z, a3); a3 = fmaf(w3.w, xv.w, a3);
    }
    zb[(uwv << 8) + (0 << 6) + lane] = a0;
    zb[(uwv << 8) + (1 << 6) + lane] = a1;
    zb[(uwv << 8) + (2 << 6) + lane] = a2;
    zb[(uwv << 8) + (3 << 6) + lane] = a3;
    __syncthreads();
    if (tid < 256) {
        const int r = tid >> 6, b = tid & 63;
        float s = linb[hu0 + r];
        #pragma unroll
        for (int w = 0; w < 8; ++w) s += zb[(w << 8) + (r << 6) + b];
        logits[((hu0 + r) << 6) + b] = s;
    }
}

// per-batch-row log-softmax + greedy argmax + masked NLL. blocks 0..63 active.
__device__ __forceinline__ void softmax_phase(
    float* __restrict__ smem_f, int* __restrict__ smem_i, int t,
    const float* __restrict__ logits, const int* __restrict__ tag_ids,
    float* __restrict__ out, int* __restrict__ deint, float* __restrict__ loss)
{
    if (blockIdx.x >= Bz) return;
    const int b = blockIdx.x, tid = threadIdx.x;
    float* s_v = smem_f;          // [512]
    float* s_r = smem_f + 512;    // [512]
    float* s_tgt = smem_f + 1024; // [1]
    int*   s_i = smem_i;          // [512]

    const float v0 = logits[(tid << 6) + b];
    const float v1 = logits[((tid + 512) << 6) + b];

    float bv = v0; int bi = tid;
    if (v1 > bv) { bv = v1; bi = tid + 512; }
    s_v[tid] = bv; s_i[tid] = bi;
    __syncthreads();
    for (int s = 256; s > 0; s >>= 1) {
        if (tid < s) {
            const float v2 = s_v[tid + s]; const int i2 = s_i[tid + s];
            if (v2 > s_v[tid] || (v2 == s_v[tid] && i2 < s_i[tid])) {
                s_v[tid] = v2; s_i[tid] = i2;
            }
        }
        __syncthreads();
    }
    const float gmax = s_v[0];
    const int   gam  = s_i[0];

    s_r[tid] = expf(v0 - gmax) + expf(v1 - gmax);
    const int tgt = tag_ids[b * TLz + t];
    if (tid == tgt) s_tgt[0] = v0;          // tgt < 74 < 512
    __syncthreads();
    for (int s = 256; s > 0; s >>= 1) {
        if (tid < s) s_r[tid] += s_r[tid + s];
        __syncthreads();
    }
    const float lse = gmax + logf(s_r[0]);

    float* orow = out + (((size_t)t * Bz + b) << 10);
    orow[tid]       = v0 - lse;
    orow[tid + 512] = v1 - lse;

    if (tid == 0) {
        deint[b] = gam;
        if (tgt != 0) {   // PAD == 0
            int cnt = 0;
            for (int bb = 0; bb < Bz; ++bb)
                cnt += (tag_ids[bb * TLz + t] != 0) ? 1 : 0;
            if (cnt < 1) cnt = 1;
            atomicAdd(loss, (lse - s_tgt[0]) / (float)cnt);
        }
    }
    __syncthreads();
}

__global__ void __launch_bounds__(TPB) seq2seq_kernel(
    const int* __restrict__ input_ids, const int* __restrict__ tag_ids,
    const float* __restrict__ enc_embed,
    const float* __restrict__ eW0, const float* __restrict__ eU0, const float* __restrict__ eb0,
    const float* __restrict__ eW1, const float* __restrict__ eU1, const float* __restrict__ eb1,
    const float* __restrict__ dec_embed,
    const float* __restrict__ dW0, const float* __restrict__ dU0, const float* __restrict__ db0,
    const float* __restrict__ dW1, const float* __restrict__ dU1, const float* __restrict__ db1,
    const float* __restrict__ linW, const float* __restrict__ linb,
    float* __restrict__ out, float* __restrict__ wsf)
{
    __shared__ float smem_f[10240];
    __shared__ int   smem_i[512];

    // ws layout (floats); h buffers are 4-k-packed [256][64][4]
    float* h0a = wsf;                 // 65536
    float* h0b = wsf + 65536;
    float* h1a = wsf + 131072;
    float* h1b = wsf + 196608;
    float* c0  = wsf + 262144;        // [1024][64]
    float* c1  = wsf + 327680;
    float* logits = wsf + 393216;     // [1024][64]
    int*   deint  = (int*)(wsf + 458752);   // [64]
    int*   gbar   = (int*)(wsf + 458816);   // barrier state (zeroed by memset)
    float* loss   = out + (size_t)TLz * Bz * Hz;

    // workspace (h/c/logits/deint/barrier) pre-zeroed by hipMemsetAsync.
    if (blockIdx.x == 0 && threadIdx.x == 0) *loss = 0.0f;

    int epoch = 0;

    float* h0c = h0a; float* h0n = h0b;
    float* h1c = h1a; float* h1n = h1b;

    // ---------------- encoder ----------------
    for (int t = 0; t < SLz; ++t) {
        lstm_phase<true>(smem_f, enc_embed, input_ids, SLz, t, nullptr, Ez,
                         eW0, eU0, eb0, h0c, h0n, c0);
        gsync(gbar, ++epoch);
        lstm_phase<false>(smem_f, nullptr, nullptr, 0, 0, h0n, Hz,
                          eW1, eU1, eb1, h1c, h1n, c1);
        gsync(gbar, ++epoch);
        float* tmp = h0c; h0c = h0n; h0n = tmp;
        tmp = h1c; h1c = h1n; h1n = tmp;
    }

    // ---------------- decoder ----------------
    for (int t = 0; t < TLz; ++t) {
        lstm_phase<true>(smem_f, dec_embed, deint, 1, 0, nullptr, Ez,
                         dW0, dU0, db0, h0c, h0n, c0);
        gsync(gbar, ++epoch);
        lstm_phase<false>(smem_f, nullptr, nullptr, 0, 0, h0n, Hz,
                          dW1, dU1, db1, h1c, h1n, c1);
        gsync(gbar, ++epoch);
        head_phase(smem_f, linW, linb, h1n, logits);
        gsync(gbar, ++epoch);
        softmax_phase(smem_f, smem_i, t, logits, tag_ids, out, deint, loss);
        gsync(gbar, ++epoch);
        float* tmp = h0c; h0c = h0n; h0n = tmp;
        tmp = h1c; h1c = h1n; h1n = tmp;
    }
}

extern "C" void kernel_launch(void* const* d_in, const int* in_sizes, int n_in,
                              void* d_out, int out_size, void* d_ws, size_t ws_size,
                              hipStream_t stream) {
    const int*   input_ids = (const int*)d_in[0];
    const int*   tag_ids   = (const int*)d_in[1];
    const float* enc_embed = (const float*)d_in[2];
    const float* eW0 = (const float*)d_in[3];
    const float* eU0 = (const float*)d_in[4];
    const float* eb0 = (const float*)d_in[5];
    const float* eW1 = (const float*)d_in[6];
    const float* eU1 = (const float*)d_in[7];
    const float* eb1 = (const float*)d_in[8];
    const float* dec_embed = (const float*)d_in[9];
    const float* dW0 = (const float*)d_in[10];
    const float* dU0 = (const float*)d_in[11];
    const float* db0 = (const float*)d_in[12];
    const float* dW1 = (const float*)d_in[13];
    const float* dU1 = (const float*)d_in[14];
    const float* db1 = (const float*)d_in[15];
    const float* linW = (const float*)d_in[16];
    const float* linb = (const float*)d_in[17];
    float* out = (float*)d_out;
    float* wsf = (float*)d_ws;

    // zero h/c/logits/deint + barrier state (stream-ordered, capture-safe)
    (void)hipMemsetAsync(d_ws, 0, (size_t)459136 * sizeof(float), stream);

    void* args[] = { &input_ids, &tag_ids, &enc_embed,
                     &eW0, &eU0, &eb0, &eW1, &eU1, &eb1,
                     &dec_embed, &dW0, &dU0, &db0, &dW1, &dU1, &db1,
                     &linW, &linb, &out, &wsf };
    (void)hipLaunchCooperativeKernel(seq2seq_kernel, dim3(NBLK), dim3(TPB),
                                     args, 0u, stream);
}

// Round 10
// 36335.022 us; speedup vs baseline: 1.6558x; 1.6558x over previous
//
#include <hip/hip_runtime.h>
#include <hip/hip_cooperative_groups.h>
#include <math.h>

namespace cg = cooperative_groups;

#define Bz  64
#define Ez  512
#define Hz  1024
#define SLz 128
#define TLz 128
#define NBLK 256
#define TPB 512
#define NGRP 16

// packed x layout: element (k, b) at ((k>>2)<<8) + (b<<2) + (k&3)
#define XPK(k, b) ((((k) >> 2) << 8) + ((b) << 2) + ((k) & 3))

// smem_f float layout (lstm phase):
//   wT [128][20]  = 2560 floats  (weights transposed: k-major, 16 rows + pad4)
//   xB [128][64]  = 8192 floats  (x transposed: k-major, 64 batches)
//   zb [8][16][64] = 8192 floats (per-wave partial C; ALIASES xB, written
//                                 only after the last compute barrier)
// total 10752 floats = 42 KiB (+2 KiB smem_i) -> 1 block/CU, coop launch OK.
#define WTS    20
#define XB_OFF 2560
#define ZB_OFF 2560

// ---------------------------------------------------------------------------
// Two-level grid barrier (proven round 6).
// ---------------------------------------------------------------------------
__device__ __forceinline__ void gsync(int* bar, int e) {
    __syncthreads();
    if (threadIdx.x == 0) {
        __threadfence();   // release
        int* gcnt = bar + ((blockIdx.x & (NGRP - 1)) << 4);
        int* rcnt = bar + (NGRP << 4);
        int* flag = bar + (NGRP << 4) + 16;
        const int gsz = NBLK / NGRP;
        bool done = false;
        if (__hip_atomic_fetch_add(gcnt, 1, __ATOMIC_ACQ_REL,
                                   __HIP_MEMORY_SCOPE_AGENT) == e * gsz - 1) {
            if (__hip_atomic_fetch_add(rcnt, 1, __ATOMIC_ACQ_REL,
                                       __HIP_MEMORY_SCOPE_AGENT) == e * NGRP - 1) {
                __hip_atomic_store(flag, e, __ATOMIC_RELEASE,
                                   __HIP_MEMORY_SCOPE_AGENT);
                done = true;
            }
        }
        if (!done) {
            while (__hip_atomic_load(flag, __ATOMIC_ACQUIRE,
                                     __HIP_MEMORY_SCOPE_AGENT) < e) {
                __builtin_amdgcn_s_sleep(2);
            }
        }
        __threadfence();   // acquire
    }
    __syncthreads();
}

// ---------------------------------------------------------------------------
// One LSTM layer, one timestep, 4 hidden units (16 gate-rows) per block.
// Outer-product register tiling: lane (bq=lane&15, rg=lane>>4) accumulates a
// 4-row x 4-batch C tile (16 regs). 8 waves split each round's 128 k into
// 16-k slices; cross-wave partials reduced via zb at the end of the phase.
// Per k: 1 b128 of wT (4 rows, 16-lane broadcast groups) + 1 b128 of xB
// (4 batches, 4-lane broadcast groups) feed 16 FMAs -> LDS traffic per FMA
// is 8x lower than the round-8 per-row broadcast scheme.
// Round: issue global loads -> scatter b32 to wT/xB -> barrier -> compute
// own 16-k slice -> barrier.
// ---------------------------------------------------------------------------
template <bool EMB>
__device__ __forceinline__ void lstm_phase(
    float* __restrict__ smem_f,
    const float* __restrict__ embed, const int* __restrict__ ids,
    int ids_stride, int ids_off,
    const float* __restrict__ xPK, int Dx,
    const float* __restrict__ Wih, const float* __restrict__ Whh,
    const float* __restrict__ bias,
    const float* __restrict__ hinPK, float* __restrict__ houtPK,
    float* __restrict__ cst)
{
    float* wT = smem_f;
    float* xB = smem_f + XB_OFF;
    float* zb = smem_f + ZB_OFF;   // aliases xB (used post-compute only)
    const int tid  = threadIdx.x;
    const int lane = tid & 63;
    const int wv   = tid >> 6;        // 0..7
    const int bq   = lane & 15;       // batch quad
    const int rg   = lane >> 4;       // row quad
    const int hu0  = blockIdx.x << 2; // unit-group base
    const int K    = Dx + Hz;
    const int NT   = K >> 7;          // rounds of 128 k

    // weight staging role: thread -> (row sr 0..15, k-quad skq 0..31)
    const int sr  = tid & 15;
    const int skq = tid >> 4;
    const int srow = ((sr >> 2) << 10) + hu0 + (sr & 3);  // global weight row

    // x staging role: (batch sb, chunk group cg); chunks kq = cg + 8j
    const int sb = tid & 63;
    const int cg = tid >> 6;
    const float* xrs = nullptr;
    if (EMB) {
        const int idx = ids[sb * ids_stride + ids_off];
        xrs = embed + (size_t)idx * Dx;
    }

    float4 a0, a1, a2, a3;   // a{r}.{j}: C[rg*4+r][bq*4+j]
    a0.x=0.f;a0.y=0.f;a0.z=0.f;a0.w=0.f;
    a1.x=0.f;a1.y=0.f;a1.z=0.f;a1.w=0.f;
    a2.x=0.f;a2.y=0.f;a2.z=0.f;a2.w=0.f;
    a3.x=0.f;a3.y=0.f;a3.z=0.f;a3.w=0.f;

    for (int rnd = 0; rnd < NT; ++rnd) {
        const int kb = rnd << 7;

        // ---- issue all global loads for this round first ----
        const int kgw = kb + (skq << 2);
        const float* wsrc = (kgw < Dx)
            ? (Wih + (size_t)srow * Dx + kgw)
            : (Whh + ((size_t)srow << 10) + (kgw - Dx));
        const float4 wv4 = *(const float4*)wsrc;

        const int kq0 = cg;            // + 8j, j = 0..3
        float4 xv0, xv1, xv2, xv3;
        {
            const int kg = kb + (kq0 << 2);
            const float* s = (kg < Dx)
                ? (EMB ? (xrs + kg) : (xPK + (kg << 6) + (sb << 2)))
                : (hinPK + ((kg - Dx) << 6) + (sb << 2));
            xv0 = *(const float4*)s;
        }
        {
            const int kg = kb + ((kq0 + 8) << 2);
            const float* s = (kg < Dx)
                ? (EMB ? (xrs + kg) : (xPK + (kg << 6) + (sb << 2)))
                : (hinPK + ((kg - Dx) << 6) + (sb << 2));
            xv1 = *(const float4*)s;
        }
        {
            const int kg = kb + ((kq0 + 16) << 2);
            const float* s = (kg < Dx)
                ? (EMB ? (xrs + kg) : (xPK + (kg << 6) + (sb << 2)))
                : (hinPK + ((kg - Dx) << 6) + (sb << 2));
            xv2 = *(const float4*)s;
        }
        {
            const int kg = kb + ((kq0 + 24) << 2);
            const float* s = (kg < Dx)
                ? (EMB ? (xrs + kg) : (xPK + (kg << 6) + (sb << 2)))
                : (hinPK + ((kg - Dx) << 6) + (sb << 2));
            xv3 = *(const float4*)s;
        }

        // ---- scatter to transposed LDS layouts (b32, conflict-light) ----
        {
            const int kl = skq << 2;
            wT[(kl + 0) * WTS + sr] = wv4.x;
            wT[(kl + 1) * WTS + sr] = wv4.y;
            wT[(kl + 2) * WTS + sr] = wv4.z;
            wT[(kl + 3) * WTS + sr] = wv4.w;
        }
        {
            const int kl = kq0 << 2;
            xB[((kl + 0) << 6) + sb] = xv0.x;
            xB[((kl + 1) << 6) + sb] = xv0.y;
            xB[((kl + 2) << 6) + sb] = xv0.z;
            xB[((kl + 3) << 6) + sb] = xv0.w;
        }
        {
            const int kl = (kq0 + 8) << 2;
            xB[((kl + 0) << 6) + sb] = xv1.x;
            xB[((kl + 1) << 6) + sb] = xv1.y;
            xB[((kl + 2) << 6) + sb] = xv1.z;
            xB[((kl + 3) << 6) + sb] = xv1.w;
        }
        {
            const int kl = (kq0 + 16) << 2;
            xB[((kl + 0) << 6) + sb] = xv2.x;
            xB[((kl + 1) << 6) + sb] = xv2.y;
            xB[((kl + 2) << 6) + sb] = xv2.z;
            xB[((kl + 3) << 6) + sb] = xv2.w;
        }
        {
            const int kl = (kq0 + 24) << 2;
            xB[((kl + 0) << 6) + sb] = xv3.x;
            xB[((kl + 1) << 6) + sb] = xv3.y;
            xB[((kl + 2) << 6) + sb] = xv3.z;
            xB[((kl + 3) << 6) + sb] = xv3.w;
        }
        __syncthreads();

        // ---- compute own 16-k slice: outer product 4x4 per lane ----
        const int k0 = wv << 4;
        #pragma unroll
        for (int kk = 0; kk < 16; ++kk) {
            const int k = k0 + kk;
            const float4 xq = *(const float4*)&xB[(k << 6) + (bq << 2)];
            const float4 wq = *(const float4*)&wT[k * WTS + (rg << 2)];
            a0.x = fmaf(wq.x, xq.x, a0.x); a0.y = fmaf(wq.x, xq.y, a0.y);
            a0.z = fmaf(wq.x, xq.z, a0.z); a0.w = fmaf(wq.x, xq.w, a0.w);
            a1.x = fmaf(wq.y, xq.x, a1.x); a1.y = fmaf(wq.y, xq.y, a1.y);
            a1.z = fmaf(wq.y, xq.z, a1.z); a1.w = fmaf(wq.y, xq.w, a1.w);
            a2.x = fmaf(wq.z, xq.x, a2.x); a2.y = fmaf(wq.z, xq.y, a2.y);
            a2.z = fmaf(wq.z, xq.z, a2.z); a2.w = fmaf(wq.z, xq.w, a2.w);
            a3.x = fmaf(wq.w, xq.x, a3.x); a3.y = fmaf(wq.w, xq.y, a3.y);
            a3.z = fmaf(wq.w, xq.z, a3.z); a3.w = fmaf(wq.w, xq.w, a3.w);
        }
        __syncthreads();
    }

    // ---- per-wave partials to zb[wave][row][batch] (aliases xB, now dead) --
    {
        const int base = (wv << 10) + (bq << 2);
        *(float4*)&zb[base + (((rg << 2) + 0) << 6)] = a0;
        *(float4*)&zb[base + (((rg << 2) + 1) << 6)] = a1;
        *(float4*)&zb[base + (((rg << 2) + 2) << 6)] = a2;
        *(float4*)&zb[base + (((rg << 2) + 3) << 6)] = a3;
    }
    __syncthreads();

    if (tid < 256) {
        const int u = tid >> 6, b = tid & 63;
        float zi = 0.f, zf = 0.f, zg = 0.f, zo = 0.f;
        #pragma unroll
        for (int w8 = 0; w8 < 8; ++w8) {
            const int base = (w8 << 10) + b;
            zi += zb[base + ((u)      << 6)];
            zf += zb[base + ((4 + u)  << 6)];
            zg += zb[base + ((8 + u)  << 6)];
            zo += zb[base + ((12 + u) << 6)];
        }
        zi += bias[hu0 + u];
        zf += bias[1024 + hu0 + u];
        zg += bias[2048 + hu0 + u];
        zo += bias[3072 + hu0 + u];
        const int hk = hu0 + u;
        const float cold = cst[(hk << 6) + b];
        const float ig = 1.0f / (1.0f + expf(-zi));
        const float fg = 1.0f / (1.0f + expf(-zf));
        const float gg = tanhf(zg);
        const float og = 1.0f / (1.0f + expf(-zo));
        const float cnew = fg * cold + ig * gg;
        cst[(hk << 6) + b] = cnew;
        houtPK[XPK(hk, b)] = og * tanhf(cnew);
    }
}

// logits[row][b] = linb[row] + sum_k linW[row][k] * h1[k][b]
// block = 4 rows; 8 waves K-split 8; LDS staging of the 4 full weight rows.
// (round-8 version, proven)
__device__ __forceinline__ void head_phase(
    float* __restrict__ smem_f,
    const float* __restrict__ linW, const float* __restrict__ linb,
    const float* __restrict__ h1PK, float* __restrict__ logits)
{
    float* wt = smem_f;          // [4][1024]
    float* zb = smem_f + 4096;   // [8][4][64]
    const int tid = threadIdx.x, lane = tid & 63, wv = tid >> 6;
    const int hu0 = blockIdx.x << 2;
    {
        const int f0 = tid << 3;               // 8 floats per thread
        const int r = f0 >> 10, k0 = f0 & 1023;
        const float* src = linW + (((size_t)(hu0 + r)) << 10) + k0;
        *(float4*)&wt[f0]     = *(const float4*)src;
        *(float4*)&wt[f0 + 4] = *(const float4*)(src + 4);
    }
    __syncthreads();
    float a0 = 0.f, a1 = 0.f, a2 = 0.f, a3 = 0.f;
    const int kb = wv << 7;   // 128-k slice per wave
    #pragma unroll 4
    for (int kl = 0; kl < 128; kl += 4) {
        const int k = kb + kl;
        const float4 xv = *(const float4*)(h1PK + ((k >> 2) << 8) + (lane << 2));
        const float4 w0 = *(const float4*)&wt[k];
        const float4 w1 = *(const float4*)&wt[1024 + k];
        const float4 w2 = *(const float4*)&wt[2048 + k];
        const float4 w3 = *(const float4*)&wt[3072 + k];
        a0 = fmaf(w0.x, xv.x, a0); a0 = fmaf(w0.y, xv.y, a0);
        a0 = fmaf(w0.z, xv.z, a0); a0 = fmaf(w0.w, xv.w, a0);
        a1 = fmaf(w1.x, xv.x, a1); a1 = fmaf(w1.y, xv.y, a1);
        a1 = fmaf(w1.z, xv.z, a1); a1 = fmaf(w1.w, xv.w, a1);
        a2 = fmaf(w2.x, xv.x, a2); a2 = fmaf(w2.y, xv.y, a2);
        a2 = fmaf(w2.z, xv.z, a2); a2 = fmaf(w2.w, xv.w, a2);
        a3 = fmaf(w3.x, xv.x, a3); a3 = fmaf(w3.y, xv.y, a3);
        a3 = fmaf(w3.z, xv.z, a3); a3 = fmaf(w3.w, xv.w, a3);
    }
    zb[(wv << 8) + (0 << 6) + lane] = a0;
    zb[(wv << 8) + (1 << 6) + lane] = a1;
    zb[(wv << 8) + (2 << 6) + lane] = a2;
    zb[(wv << 8) + (3 << 6) + lane] = a3;
    __syncthreads();
    if (tid < 256) {
        const int r = tid >> 6, b = tid & 63;
        float s = linb[hu0 + r];
        #pragma unroll
        for (int w = 0; w < 8; ++w) s += zb[(w << 8) + (r << 6) + b];
        logits[((hu0 + r) << 6) + b] = s;
    }
}

// per-batch-row log-softmax + greedy argmax + masked NLL. blocks 0..63 active.
__device__ __forceinline__ void softmax_phase(
    float* __restrict__ smem_f, int* __restrict__ smem_i, int t,
    const float* __restrict__ logits, const int* __restrict__ tag_ids,
    float* __restrict__ out, int* __restrict__ deint, float* __restrict__ loss)
{
    if (blockIdx.x >= Bz) return;
    const int b = blockIdx.x, tid = threadIdx.x;
    float* s_v = smem_f;          // [512]
    float* s_r = smem_f + 512;    // [512]
    float* s_tgt = smem_f + 1024; // [1]
    int*   s_i = smem_i;          // [512]

    const float v0 = logits[(tid << 6) + b];
    const float v1 = logits[((tid + 512) << 6) + b];

    float bv = v0; int bi = tid;
    if (v1 > bv) { bv = v1; bi = tid + 512; }
    s_v[tid] = bv; s_i[tid] = bi;
    __syncthreads();
    for (int s = 256; s > 0; s >>= 1) {
        if (tid < s) {
            const float v2 = s_v[tid + s]; const int i2 = s_i[tid + s];
            if (v2 > s_v[tid] || (v2 == s_v[tid] && i2 < s_i[tid])) {
                s_v[tid] = v2; s_i[tid] = i2;
            }
        }
        __syncthreads();
    }
    const float gmax = s_v[0];
    const int   gam  = s_i[0];

    s_r[tid] = expf(v0 - gmax) + expf(v1 - gmax);
    const int tgt = tag_ids[b * TLz + t];
    if (tid == tgt) s_tgt[0] = v0;          // tgt < 74 < 512
    __syncthreads();
    for (int s = 256; s > 0; s >>= 1) {
        if (tid < s) s_r[tid] += s_r[tid + s];
        __syncthreads();
    }
    const float lse = gmax + logf(s_r[0]);

    float* orow = out + (((size_t)t * Bz + b) << 10);
    orow[tid]       = v0 - lse;
    orow[tid + 512] = v1 - lse;

    if (tid == 0) {
        deint[b] = gam;
        if (tgt != 0) {   // PAD == 0
            int cnt = 0;
            for (int bb = 0; bb < Bz; ++bb)
                cnt += (tag_ids[bb * TLz + t] != 0) ? 1 : 0;
            if (cnt < 1) cnt = 1;
            atomicAdd(loss, (lse - s_tgt[0]) / (float)cnt);
        }
    }
    __syncthreads();
}

__global__ void __launch_bounds__(TPB) seq2seq_kernel(
    const int* __restrict__ input_ids, const int* __restrict__ tag_ids,
    const float* __restrict__ enc_embed,
    const float* __restrict__ eW0, const float* __restrict__ eU0, const float* __restrict__ eb0,
    const float* __restrict__ eW1, const float* __restrict__ eU1, const float* __restrict__ eb1,
    const float* __restrict__ dec_embed,
    const float* __restrict__ dW0, const float* __restrict__ dU0, const float* __restrict__ db0,
    const float* __restrict__ dW1, const float* __restrict__ dU1, const float* __restrict__ db1,
    const float* __restrict__ linW, const float* __restrict__ linb,
    float* __restrict__ out, float* __restrict__ wsf)
{
    __shared__ float smem_f[10752];
    __shared__ int   smem_i[512];

    // ws layout (floats); h buffers are 4-k-packed [256][64][4]
    float* h0a = wsf;                 // 65536
    float* h0b = wsf + 65536;
    float* h1a = wsf + 131072;
    float* h1b = wsf + 196608;
    float* c0  = wsf + 262144;        // [1024][64]
    float* c1  = wsf + 327680;
    float* logits = wsf + 393216;     // [1024][64]
    int*   deint  = (int*)(wsf + 458752);   // [64]
    int*   gbar   = (int*)(wsf + 458816);   // barrier state (zeroed by memset)
    float* loss   = out + (size_t)TLz * Bz * Hz;

    // workspace (h/c/logits/deint/barrier) pre-zeroed by hipMemsetAsync.
    if (blockIdx.x == 0 && threadIdx.x == 0) *loss = 0.0f;

    int epoch = 0;

    float* h0c = h0a; float* h0n = h0b;
    float* h1c = h1a; float* h1n = h1b;

    // ---------------- encoder ----------------
    for (int t = 0; t < SLz; ++t) {
        lstm_phase<true>(smem_f, enc_embed, input_ids, SLz, t, nullptr, Ez,
                         eW0, eU0, eb0, h0c, h0n, c0);
        gsync(gbar, ++epoch);
        lstm_phase<false>(smem_f, nullptr, nullptr, 0, 0, h0n, Hz,
                          eW1, eU1, eb1, h1c, h1n, c1);
        gsync(gbar, ++epoch);
        float* tmp = h0c; h0c = h0n; h0n = tmp;
        tmp = h1c; h1c = h1n; h1n = tmp;
    }

    // ---------------- decoder ----------------
    for (int t = 0; t < TLz; ++t) {
        lstm_phase<true>(smem_f, dec_embed, deint, 1, 0, nullptr, Ez,
                         dW0, dU0, db0, h0c, h0n, c0);
        gsync(gbar, ++epoch);
        lstm_phase<false>(smem_f, nullptr, nullptr, 0, 0, h0n, Hz,
                          dW1, dU1, db1, h1c, h1n, c1);
        gsync(gbar, ++epoch);
        head_phase(smem_f, linW, linb, h1n, logits);
        gsync(gbar, ++epoch);
        softmax_phase(smem_f, smem_i, t, logits, tag_ids, out, deint, loss);
        gsync(gbar, ++epoch);
        float* tmp = h0c; h0c = h0n; h0n = tmp;
        tmp = h1c; h1c = h1n; h1n = tmp;
    }
}

extern "C" void kernel_launch(void* const* d_in, const int* in_sizes, int n_in,
                              void* d_out, int out_size, void* d_ws, size_t ws_size,
                              hipStream_t stream) {
    const int*   input_ids = (const int*)d_in[0];
    const int*   tag_ids   = (const int*)d_in[1];
    const float* enc_embed = (const float*)d_in[2];
    const float* eW0 = (const float*)d_in[3];
    const float* eU0 = (const float*)d_in[4];
    const float* eb0 = (const float*)d_in[5];
    const float* eW1 = (const float*)d_in[6];
    const float* eU1 = (const float*)d_in[7];
    const float* eb1 = (const float*)d_in[8];
    const float* dec_embed = (const float*)d_in[9];
    const float* dW0 = (const float*)d_in[10];
    const float* dU0 = (const float*)d_in[11];
    const float* db0 = (const float*)d_in[12];
    const float* dW1 = (const float*)d_in[13];
    const float* dU1 = (const float*)d_in[14];
    const float* db1 = (const float*)d_in[15];
    const float* linW = (const float*)d_in[16];
    const float* linb = (const float*)d_in[17];
    float* out = (float*)d_out;
    float* wsf = (float*)d_ws;

    // zero h/c/logits/deint + barrier state (stream-ordered, capture-safe)
    (void)hipMemsetAsync(d_ws, 0, (size_t)459136 * sizeof(float), stream);

    void* args[] = { &input_ids, &tag_ids, &enc_embed,
                     &eW0, &eU0, &eb0, &eW1, &eU1, &eb1,
                     &dec_embed, &dW0, &dU0, &db0, &dW1, &dU1, &db1,
                     &linW, &linb, &out, &wsf };
    (void)hipLaunchCooperativeKernel(seq2seq_kernel, dim3(NBLK), dim3(TPB),
                                     args, 0u, stream);
}